// Round 1
// baseline (471.393 us; speedup 1.0000x reference)
//
#include <hip/hip_runtime.h>
#include <math.h>

// Problem constants (fixed by reference)
#define ROWS   8192      // BS * T * HW
#define LQ     4096      // T * HW
#define DMODEL 256
#define NHEAD  8
#define NLVL   4
#define NPTS   4
#define HDIM   32
#define DFFN_  1024
#define GRID_W 32        // W = H = 32 per level

// ---------------------------------------------------------------------------
// Generic fp32 SGEMM: C[M,N] = A[M,K] @ B[K,N] + bias (+res) (relu optional)
// 64x64 tile, 256 threads, 4x4 micro-tile per thread, K-step 16.
// M,N multiples of 64; K multiple of 16.
// ---------------------------------------------------------------------------
template<bool RELU, bool RES>
__global__ __launch_bounds__(256) void sgemm_k(
    const float* __restrict__ A, const float* __restrict__ B,
    const float* __restrict__ bias, const float* __restrict__ res,
    float* __restrict__ C, int M, int N, int K)
{
    __shared__ float As[16][64];   // [k][row]
    __shared__ float Bs[16][64];   // [k][col]
    const int tid = threadIdx.x;
    const int tx = tid & 15, ty = tid >> 4;
    const int row0 = blockIdx.y << 6, col0 = blockIdx.x << 6;
    // A-tile load mapping: thread -> (row=tid/4, kquad=(tid%4)*4)
    const int ar = tid >> 2;
    const int aq = (tid & 3) << 2;
    // B-tile load mapping: thread -> (k=tid/16, n=(tid%16)*4)
    const int bk = tid >> 4;
    const int bn = (tid & 15) << 2;

    float acc[4][4] = {{0.f,0.f,0.f,0.f},{0.f,0.f,0.f,0.f},
                       {0.f,0.f,0.f,0.f},{0.f,0.f,0.f,0.f}};

    for (int k0 = 0; k0 < K; k0 += 16) {
        float4 av = *(const float4*)(A + (size_t)(row0 + ar) * K + k0 + aq);
        float4 bv = *(const float4*)(B + (size_t)(k0 + bk) * N + col0 + bn);
        __syncthreads();
        As[aq + 0][ar] = av.x;
        As[aq + 1][ar] = av.y;
        As[aq + 2][ar] = av.z;
        As[aq + 3][ar] = av.w;
        *(float4*)&Bs[bk][bn] = bv;
        __syncthreads();
        #pragma unroll
        for (int kk = 0; kk < 16; kk++) {
            const float* ap = &As[kk][ty << 2];
            const float* bp = &Bs[kk][tx << 2];
            float a0 = ap[0], a1 = ap[1], a2 = ap[2], a3 = ap[3];
            float b0 = bp[0], b1 = bp[1], b2 = bp[2], b3 = bp[3];
            acc[0][0] += a0 * b0; acc[0][1] += a0 * b1; acc[0][2] += a0 * b2; acc[0][3] += a0 * b3;
            acc[1][0] += a1 * b0; acc[1][1] += a1 * b1; acc[1][2] += a1 * b2; acc[1][3] += a1 * b3;
            acc[2][0] += a2 * b0; acc[2][1] += a2 * b1; acc[2][2] += a2 * b2; acc[2][3] += a2 * b3;
            acc[3][0] += a3 * b0; acc[3][1] += a3 * b1; acc[3][2] += a3 * b2; acc[3][3] += a3 * b3;
        }
    }

    float4 bi = *(const float4*)(bias + col0 + (tx << 2));
    #pragma unroll
    for (int i = 0; i < 4; i++) {
        int row = row0 + (ty << 2) + i;
        float4 o;
        o.x = acc[i][0] + bi.x;
        o.y = acc[i][1] + bi.y;
        o.z = acc[i][2] + bi.z;
        o.w = acc[i][3] + bi.w;
        if (RELU) {
            o.x = fmaxf(o.x, 0.f); o.y = fmaxf(o.y, 0.f);
            o.z = fmaxf(o.z, 0.f); o.w = fmaxf(o.w, 0.f);
        }
        if (RES) {
            float4 rv = *(const float4*)(res + (size_t)row * N + col0 + (tx << 2));
            o.x += rv.x; o.y += rv.y; o.z += rv.z; o.w += rv.w;
        }
        *(float4*)(C + (size_t)row * N + col0 + (tx << 2)) = o;
    }
}

// ---------------------------------------------------------------------------
// sampling_locations[idx] = ref[r*8 + l*2 + c] + off[idx] / 32
// idx layout (r, h, l, p, c): strides 256/32/8/2/1 — matches offsets GEMM cols.
// ---------------------------------------------------------------------------
__global__ __launch_bounds__(256) void samp_loc_k(
    const float* __restrict__ ref, const float* __restrict__ off,
    float* __restrict__ out)
{
    int idx = blockIdx.x * 256 + threadIdx.x;   // < ROWS*256
    int c = idx & 1;
    int l = (idx >> 3) & 3;
    int r = idx >> 8;
    out[idx] = ref[(r << 3) + (l << 1) + c] + off[idx] * (1.f / 32.f);
}

// ---------------------------------------------------------------------------
// softmax over 16 (NL*NP) per (row, head); in-place. 65536 items.
// ---------------------------------------------------------------------------
__global__ __launch_bounds__(256) void softmax16_k(float* __restrict__ a)
{
    int idx = blockIdx.x * 256 + threadIdx.x;   // r*8+h
    float v[16];
    float m = -1e30f;
    #pragma unroll
    for (int i = 0; i < 16; i++) { v[i] = a[idx * 16 + i]; m = fmaxf(m, v[i]); }
    float s = 0.f;
    #pragma unroll
    for (int i = 0; i < 16; i++) { v[i] = __expf(v[i] - m); s += v[i]; }
    float inv = 1.f / s;
    #pragma unroll
    for (int i = 0; i < 16; i++) a[idx * 16 + i] = v[i] * inv;
}

// ---------------------------------------------------------------------------
// Deformable bilinear gather.
// Block = 256 threads = 8 groups x 32 lanes; group -> one (r,h), lane -> d.
// out[r*256 + h*32 + d] = sum_{l,p} w * bilinear(value_level_l_head_h, loc)
// ---------------------------------------------------------------------------
__global__ __launch_bounds__(256) void deform_gather_k(
    const float* __restrict__ value, const float* __restrict__ loc,
    const float* __restrict__ attw, float* __restrict__ out)
{
    int tid = threadIdx.x;
    int grp = tid >> 5, d = tid & 31;
    int gid = blockIdx.x * 8 + grp;           // = r*8 + h, < 65536
    int h = gid & 7, r = gid >> 3;
    int bbase = (r >> 12) << 12;              // b * LQ
    float acc = 0.f;
    #pragma unroll
    for (int l = 0; l < 4; l++) {
        int rowbase = bbase + (l << 10);      // level start = l*1024
        #pragma unroll
        for (int p = 0; p < 4; p++) {
            int li = ((gid << 2) + l) * 8 + (p << 1);
            float lx = loc[li], ly = loc[li + 1];
            float w = attw[(gid << 4) + (l << 2) + p];
            float xf = lx * 32.f - 0.5f, yf = ly * 32.f - 0.5f;
            float x0f = floorf(xf), y0f = floorf(yf);
            float fx = xf - x0f, fy = yf - y0f;
            int x0 = (int)x0f, y0 = (int)y0f;
            #pragma unroll
            for (int dy = 0; dy < 2; dy++) {
                #pragma unroll
                for (int dx = 0; dx < 2; dx++) {
                    int xi = x0 + dx, yi = y0 + dy;
                    float wt = (dx ? fx : 1.f - fx) * (dy ? fy : 1.f - fy);
                    bool valid = (xi >= 0) & (xi < 32) & (yi >= 0) & (yi < 32);
                    int xc = min(max(xi, 0), 31), yc = min(max(yi, 0), 31);
                    float vv = value[(((size_t)(rowbase + (yc << 5) + xc) * 8 + h) << 5) + d];
                    acc += valid ? (w * wt * vv) : 0.f;
                }
            }
        }
    }
    out[(size_t)r * 256 + (h << 5) + d] = acc;
}

// ---------------------------------------------------------------------------
// In-place LayerNorm over 256 cols. One wave per row (4 rows per block).
// ---------------------------------------------------------------------------
__global__ __launch_bounds__(256) void layernorm_k(
    float* __restrict__ x, const float* __restrict__ g, const float* __restrict__ b)
{
    int lane = threadIdx.x & 63;
    int wv = threadIdx.x >> 6;
    int row = blockIdx.x * 4 + wv;
    int c = lane << 2;
    float4 v = *(const float4*)(x + (size_t)row * 256 + c);
    float s = v.x + v.y + v.z + v.w;
    #pragma unroll
    for (int o = 1; o < 64; o <<= 1) s += __shfl_xor(s, o);
    float mu = s * (1.f / 256.f);
    float d0 = v.x - mu, d1 = v.y - mu, d2 = v.z - mu, d3 = v.w - mu;
    float vs = d0 * d0 + d1 * d1 + d2 * d2 + d3 * d3;
    #pragma unroll
    for (int o = 1; o < 64; o <<= 1) vs += __shfl_xor(vs, o);
    float rstd = rsqrtf(vs * (1.f / 256.f) + 1e-5f);
    float4 gg = *(const float4*)(g + c);
    float4 bb = *(const float4*)(b + c);
    float4 o4;
    o4.x = d0 * rstd * gg.x + bb.x;
    o4.y = d1 * rstd * gg.y + bb.y;
    o4.z = d2 * rstd * gg.z + bb.z;
    o4.w = d3 * rstd * gg.w + bb.w;
    *(float4*)(x + (size_t)row * 256 + c) = o4;
}

// ---------------------------------------------------------------------------
extern "C" void kernel_launch(void* const* d_in, const int* in_sizes, int n_in,
                              void* d_out, int out_size, void* d_ws, size_t ws_size,
                              hipStream_t stream)
{
    const float* src   = (const float*)d_in[0];
    // d_in[1] = pos — unused by the reference forward
    const float* refp  = (const float*)d_in[2];
    const float* vw    = (const float*)d_in[3];
    const float* vb    = (const float*)d_in[4];
    const float* ofw   = (const float*)d_in[5];
    const float* ofb   = (const float*)d_in[6];
    const float* aww   = (const float*)d_in[7];
    const float* awb   = (const float*)d_in[8];
    const float* pw    = (const float*)d_in[9];
    const float* pb    = (const float*)d_in[10];
    const float* g1    = (const float*)d_in[11];
    const float* b1    = (const float*)d_in[12];
    const float* w1    = (const float*)d_in[13];
    const float* bi1   = (const float*)d_in[14];
    const float* w2    = (const float*)d_in[15];
    const float* bi2   = (const float*)d_in[16];
    const float* g2    = (const float*)d_in[17];
    const float* b2    = (const float*)d_in[18];

    float* ws       = (float*)d_ws;
    float* value    = ws;                 // 2,097,152 f
    float* attw     = ws + 2097152;       // 1,048,576 f
    float* attn_out = ws + 3145728;       // 2,097,152 f
    float* x1       = ws + 5242880;       // 2,097,152 f
    float* hidden   = ws + 7340032;       // 8,388,608 f (also offsets scratch)

    float* out_x   = (float*)d_out;       // 2,097,152 f
    float* out_loc = out_x + 2097152;     // 2,097,152 f

    dim3 blk(256);

    // Projections from src: value / sampling offsets / attention logits
    sgemm_k<false, false><<<dim3(4, 128), blk, 0, stream>>>(src, vw, vb, nullptr, value, ROWS, 256, 256);
    sgemm_k<false, false><<<dim3(4, 128), blk, 0, stream>>>(src, ofw, ofb, nullptr, hidden, ROWS, 256, 256);
    sgemm_k<false, false><<<dim3(2, 128), blk, 0, stream>>>(src, aww, awb, nullptr, attw, ROWS, 128, 256);

    // sampling_locations -> d_out (second chunk)
    samp_loc_k<<<8192, blk, 0, stream>>>(refp, hidden, out_loc);

    // softmax over 16 per (row, head)
    softmax16_k<<<256, blk, 0, stream>>>(attw);

    // deformable bilinear gather -> attn_out (ROWS, 256)
    deform_gather_k<<<8192, blk, 0, stream>>>(value, out_loc, attw, attn_out);

    // output projection + residual(src), then LN1 (in-place)
    sgemm_k<false, true><<<dim3(4, 128), blk, 0, stream>>>(attn_out, pw, pb, src, x1, ROWS, 256, 256);
    layernorm_k<<<2048, blk, 0, stream>>>(x1, g1, b1);

    // FFN: linear1 + ReLU -> hidden ; linear2 + residual(x1) -> out_x ; LN2
    sgemm_k<true, false><<<dim3(16, 128), blk, 0, stream>>>(x1, w1, bi1, nullptr, hidden, ROWS, 1024, 256);
    sgemm_k<false, true><<<dim3(4, 128), blk, 0, stream>>>(hidden, w2, bi2, x1, out_x, ROWS, 256, 1024);
    layernorm_k<<<2048, blk, 0, stream>>>(out_x, g2, b2);
}

// Round 2
// 245.280 us; speedup vs baseline: 1.9219x; 1.9219x over previous
//
#include <hip/hip_runtime.h>
#include <math.h>

#define ROWS   8192
#define LQ     4096
#define NHEAD  8
#define NLVL   4
#define NPTS   4
#define HDIM   32

typedef __attribute__((ext_vector_type(8))) short v8s;
typedef __attribute__((ext_vector_type(4))) float v4f;

__device__ __forceinline__ unsigned short f2bf(float x) {
    unsigned int u = __float_as_uint(x);
    u += 0x7fffu + ((u >> 16) & 1u);
    return (unsigned short)(u >> 16);
}

// ---------------------------------------------------------------------------
// fp32 -> bf16 elementwise (vectorized x4)
// ---------------------------------------------------------------------------
__global__ __launch_bounds__(256) void f2bf_k(const float* __restrict__ in,
                                              unsigned short* __restrict__ out, int n4)
{
    int i = blockIdx.x * 256 + threadIdx.x;
    if (i >= n4) return;
    float4 v = ((const float4*)in)[i];
    ushort4 o;
    o.x = f2bf(v.x); o.y = f2bf(v.y); o.z = f2bf(v.z); o.w = f2bf(v.w);
    ((ushort4*)out)[i] = o;
}

// ---------------------------------------------------------------------------
// Transpose + convert: out_bf[(n_off + n) * ldout + k] = bf16(in[k*N + n])
// K, N multiples of 32. Block 256 threads, tile 32x32.
// ---------------------------------------------------------------------------
__global__ __launch_bounds__(256) void transT_k(const float* __restrict__ in,
                                                unsigned short* __restrict__ out,
                                                int K, int N, int ldout, int n_off)
{
    __shared__ float t[32][33];
    int tid = threadIdx.x;
    int tx = tid & 31, ty = tid >> 5;           // 32 x 8
    int k0 = blockIdx.y << 5, n0 = blockIdx.x << 5;
    #pragma unroll
    for (int i = 0; i < 4; i++)
        t[ty + i * 8][tx] = in[(size_t)(k0 + ty + i * 8) * N + n0 + tx];
    __syncthreads();
    #pragma unroll
    for (int i = 0; i < 4; i++)
        out[(size_t)(n_off + n0 + ty + i * 8) * ldout + k0 + tx] = f2bf(t[tx][ty + i * 8]);
}

// ---------------------------------------------------------------------------
// Concatenate 3 bias vectors (256 + 256 + 128)
// ---------------------------------------------------------------------------
__global__ __launch_bounds__(256) void biascat_k(const float* __restrict__ a,
                                                 const float* __restrict__ b,
                                                 const float* __restrict__ c,
                                                 float* __restrict__ out)
{
    int i = blockIdx.x * 256 + threadIdx.x;
    if (i < 256) out[i] = a[i];
    else if (i < 512) out[i] = b[i - 256];
    else if (i < 640) out[i] = c[i - 512];
}

// ---------------------------------------------------------------------------
// bf16 MFMA GEMM: C[M][N] = A[M][K] @ Bt[N][K]^T + bias (+res)(relu)
// BM=128, BN=64, BK=32; 256 threads = 4 waves (2x2), each wave 64x32 via
// 4x2 tiles of 16x16x32 MFMA. K-packed LDS: [kq][row][8] so staging and
// fragment reads are both 16B-contiguous (2-way bank alias max = free).
// ---------------------------------------------------------------------------
template<bool OUTBF, bool RELU, bool RES>
__global__ __launch_bounds__(256) void mfma_gemm_k(
    const unsigned short* __restrict__ A,   // bf16 [M][K]
    const unsigned short* __restrict__ Bt,  // bf16 [N][K]
    const float* __restrict__ bias,
    const float* __restrict__ res,
    void* __restrict__ Cout,
    int M, int N, int K)
{
    __shared__ __align__(16) unsigned short As[4][128][8];
    __shared__ __align__(16) unsigned short Bs[4][64][8];
    const int tid = threadIdx.x;
    const int row0 = blockIdx.y << 7, col0 = blockIdx.x << 6;
    const int wid = tid >> 6, lane = tid & 63;
    const int wm = wid & 1, wn = wid >> 1;
    const int lr = lane & 15, kq = lane >> 4;
    const int ar = tid >> 2, akq = tid & 3;     // A staging: 2 rows/thread
    const int bn = tid >> 2, bkq = tid & 3;     // B staging: 1 row/thread

    v4f acc[4][2];
    #pragma unroll
    for (int i = 0; i < 4; i++)
        #pragma unroll
        for (int j = 0; j < 2; j++) acc[i][j] = (v4f){0.f, 0.f, 0.f, 0.f};

    for (int k0 = 0; k0 < K; k0 += 32) {
        float4 a0 = *(const float4*)(A + (size_t)(row0 + ar) * K + k0 + akq * 8);
        float4 a1 = *(const float4*)(A + (size_t)(row0 + ar + 64) * K + k0 + akq * 8);
        float4 b0 = *(const float4*)(Bt + (size_t)(col0 + bn) * K + k0 + bkq * 8);
        __syncthreads();
        *(float4*)(&As[akq][ar][0]) = a0;
        *(float4*)(&As[akq][ar + 64][0]) = a1;
        *(float4*)(&Bs[bkq][bn][0]) = b0;
        __syncthreads();
        v8s bf[2];
        #pragma unroll
        for (int nt = 0; nt < 2; nt++)
            bf[nt] = *(const v8s*)(&Bs[kq][wn * 32 + nt * 16 + lr][0]);
        #pragma unroll
        for (int mt = 0; mt < 4; mt++) {
            v8s af = *(const v8s*)(&As[kq][wm * 64 + mt * 16 + lr][0]);
            #pragma unroll
            for (int nt = 0; nt < 2; nt++)
                acc[mt][nt] = __builtin_amdgcn_mfma_f32_16x16x32_bf16(af, bf[nt], acc[mt][nt], 0, 0, 0);
        }
    }

    const int rq = lane >> 4;
    #pragma unroll
    for (int mt = 0; mt < 4; mt++) {
        #pragma unroll
        for (int nt = 0; nt < 2; nt++) {
            int col = col0 + wn * 32 + nt * 16 + lr;
            float bv = bias[col];
            #pragma unroll
            for (int i = 0; i < 4; i++) {
                int row = row0 + wm * 64 + mt * 16 + rq * 4 + i;
                float v = acc[mt][nt][i] + bv;
                if (RELU) v = fmaxf(v, 0.f);
                if (RES)  v += res[(size_t)row * N + col];
                if (OUTBF) ((unsigned short*)Cout)[(size_t)row * N + col] = f2bf(v);
                else       ((float*)Cout)[(size_t)row * N + col] = v;
            }
        }
    }
}

// ---------------------------------------------------------------------------
// Fused: sampling-loc compute (+write), softmax-16, bilinear gather.
// 8 lanes per (r,h) group, float4 over head-dim. 32 groups / 256-thr block.
// value lives in proj[.., 0:256] (row stride 640); offsets in [256:512);
// attn logits in [512:640).
// ---------------------------------------------------------------------------
__global__ __launch_bounds__(256) void fused_gather_k(
    const float* __restrict__ proj,            // [ROWS][640]
    const float* __restrict__ refp,            // [ROWS][8]
    float* __restrict__ out_loc,               // [ROWS][256]
    unsigned short* __restrict__ attn_bf)      // [ROWS][256] bf16
{
    int tid = threadIdx.x;
    int grp = tid >> 3, d4 = tid & 7;
    int gid = blockIdx.x * 32 + grp;           // r*8 + h
    int h = gid & 7, r = gid >> 3;
    int b = r >> 12;
    const float* prow = proj + (size_t)r * 640;

    float rp[8];
    *(float4*)(rp)     = *(const float4*)(refp + (size_t)r * 8);
    *(float4*)(rp + 4) = *(const float4*)(refp + (size_t)r * 8 + 4);

    float loc[32];
    #pragma unroll
    for (int i = 0; i < 8; i++)
        *(float4*)(loc + i * 4) = *(const float4*)(prow + 256 + h * 32 + i * 4);
    #pragma unroll
    for (int i = 0; i < 32; i++) {
        int l = i >> 3, c = i & 1;
        loc[i] = rp[l * 2 + c] + loc[i] * (1.f / 32.f);
    }
    *(float4*)(out_loc + (size_t)r * 256 + h * 32 + d4 * 4) = *(const float4*)(loc + d4 * 4);

    float w[16];
    #pragma unroll
    for (int i = 0; i < 4; i++)
        *(float4*)(w + i * 4) = *(const float4*)(prow + 512 + h * 16 + i * 4);
    float m = -1e30f;
    #pragma unroll
    for (int i = 0; i < 16; i++) m = fmaxf(m, w[i]);
    float s = 0.f;
    #pragma unroll
    for (int i = 0; i < 16; i++) { w[i] = __expf(w[i] - m); s += w[i]; }
    float inv = 1.f / s;
    #pragma unroll
    for (int i = 0; i < 16; i++) w[i] *= inv;

    float4 acc = {0.f, 0.f, 0.f, 0.f};
    #pragma unroll
    for (int l = 0; l < 4; l++) {
        const float* vbase = proj + ((size_t)(b * LQ + l * 1024)) * 640 + h * 32 + d4 * 4;
        #pragma unroll
        for (int p = 0; p < 4; p++) {
            float lx = loc[l * 8 + p * 2], ly = loc[l * 8 + p * 2 + 1];
            float wgt = w[l * 4 + p];
            float xf = lx * 32.f - 0.5f, yf = ly * 32.f - 0.5f;
            float x0f = floorf(xf), y0f = floorf(yf);
            float fx = xf - x0f, fy = yf - y0f;
            int x0 = (int)x0f, y0 = (int)y0f;
            #pragma unroll
            for (int dy = 0; dy < 2; dy++) {
                #pragma unroll
                for (int dx = 0; dx < 2; dx++) {
                    int xi = x0 + dx, yi = y0 + dy;
                    float wt = (dx ? fx : 1.f - fx) * (dy ? fy : 1.f - fy);
                    bool valid = (xi >= 0) & (xi < 32) & (yi >= 0) & (yi < 32);
                    int xc = min(max(xi, 0), 31), yc = min(max(yi, 0), 31);
                    float c = valid ? (wgt * wt) : 0.f;
                    float4 vv = *(const float4*)(vbase + (size_t)((yc << 5) + xc) * 640);
                    acc.x += c * vv.x; acc.y += c * vv.y;
                    acc.z += c * vv.z; acc.w += c * vv.w;
                }
            }
        }
    }
    ushort4 o;
    o.x = f2bf(acc.x); o.y = f2bf(acc.y); o.z = f2bf(acc.z); o.w = f2bf(acc.w);
    *(ushort4*)(attn_bf + (size_t)r * 256 + h * 32 + d4 * 4) = o;
}

// ---------------------------------------------------------------------------
// In-place LayerNorm over 256 cols; optional bf16 copy-out.
// ---------------------------------------------------------------------------
template<bool WRITE_BF>
__global__ __launch_bounds__(256) void layernorm_k(
    float* __restrict__ x, const float* __restrict__ g, const float* __restrict__ b,
    unsigned short* __restrict__ xbf)
{
    int lane = threadIdx.x & 63;
    int wv = threadIdx.x >> 6;
    int row = blockIdx.x * 4 + wv;
    int c = lane << 2;
    float4 v = *(const float4*)(x + (size_t)row * 256 + c);
    float s = v.x + v.y + v.z + v.w;
    #pragma unroll
    for (int o = 1; o < 64; o <<= 1) s += __shfl_xor(s, o);
    float mu = s * (1.f / 256.f);
    float d0 = v.x - mu, d1 = v.y - mu, d2 = v.z - mu, d3 = v.w - mu;
    float vs = d0 * d0 + d1 * d1 + d2 * d2 + d3 * d3;
    #pragma unroll
    for (int o = 1; o < 64; o <<= 1) vs += __shfl_xor(vs, o);
    float rstd = rsqrtf(vs * (1.f / 256.f) + 1e-5f);
    float4 gg = *(const float4*)(g + c);
    float4 bb = *(const float4*)(b + c);
    float4 o4;
    o4.x = d0 * rstd * gg.x + bb.x;
    o4.y = d1 * rstd * gg.y + bb.y;
    o4.z = d2 * rstd * gg.z + bb.z;
    o4.w = d3 * rstd * gg.w + bb.w;
    *(float4*)(x + (size_t)row * 256 + c) = o4;
    if (WRITE_BF) {
        ushort4 ob;
        ob.x = f2bf(o4.x); ob.y = f2bf(o4.y); ob.z = f2bf(o4.z); ob.w = f2bf(o4.w);
        *(ushort4*)(xbf + (size_t)row * 256 + c) = ob;
    }
}

// ---------------------------------------------------------------------------
extern "C" void kernel_launch(void* const* d_in, const int* in_sizes, int n_in,
                              void* d_out, int out_size, void* d_ws, size_t ws_size,
                              hipStream_t stream)
{
    const float* src   = (const float*)d_in[0];
    const float* refp  = (const float*)d_in[2];
    const float* vw    = (const float*)d_in[3];
    const float* vb    = (const float*)d_in[4];
    const float* ofw   = (const float*)d_in[5];
    const float* ofb   = (const float*)d_in[6];
    const float* aww   = (const float*)d_in[7];
    const float* awb   = (const float*)d_in[8];
    const float* pw    = (const float*)d_in[9];
    const float* pb    = (const float*)d_in[10];
    const float* g1    = (const float*)d_in[11];
    const float* b1    = (const float*)d_in[12];
    const float* w1    = (const float*)d_in[13];
    const float* bi1   = (const float*)d_in[14];
    const float* w2    = (const float*)d_in[15];
    const float* bi2   = (const float*)d_in[16];
    const float* g2    = (const float*)d_in[17];
    const float* b2    = (const float*)d_in[18];

    float* ws = (float*)d_ws;
    float*          proj      = ws;                              // 5,242,880 f
    float*          x1        = ws + 5242880;                    // 2,097,152 f
    unsigned short* src_bf    = (unsigned short*)(ws + 7340032); // 2,097,152 us
    unsigned short* x1_bf     = (unsigned short*)(ws + 8388608);
    unsigned short* attn_bf   = (unsigned short*)(ws + 9437184);
    unsigned short* hidden_bf = (unsigned short*)(ws + 10485760); // 8,388,608 us
    unsigned short* Btcat     = (unsigned short*)(ws + 14680064); // 163,840 us
    unsigned short* pwT       = (unsigned short*)(ws + 14761984); //  65,536 us
    unsigned short* w1T       = (unsigned short*)(ws + 14794752); // 262,144 us
    unsigned short* w2T       = (unsigned short*)(ws + 14925824); // 262,144 us
    float*          biascat   = ws + 15056896;                    // 640 f

    float* out_x   = (float*)d_out;
    float* out_loc = out_x + 2097152;

    dim3 blk(256);

    // --- weight prep (bf16, transposed) + src conversion ---
    f2bf_k<<<2048, blk, 0, stream>>>(src, src_bf, 524288);
    transT_k<<<dim3(8, 8),  blk, 0, stream>>>(vw,  Btcat, 256, 256,  256, 0);
    transT_k<<<dim3(8, 8),  blk, 0, stream>>>(ofw, Btcat, 256, 256,  256, 256);
    transT_k<<<dim3(4, 8),  blk, 0, stream>>>(aww, Btcat, 256, 128,  256, 512);
    transT_k<<<dim3(8, 8),  blk, 0, stream>>>(pw,  pwT,   256, 256,  256, 0);
    transT_k<<<dim3(32, 8), blk, 0, stream>>>(w1,  w1T,   256, 1024, 256, 0);
    transT_k<<<dim3(8, 32), blk, 0, stream>>>(w2,  w2T,  1024, 256, 1024, 0);
    biascat_k<<<3, blk, 0, stream>>>(vb, ofb, awb, biascat);

    // --- fused projections: value | offsets | attn logits -> proj[8192][640]
    mfma_gemm_k<false, false, false><<<dim3(10, 64), blk, 0, stream>>>(
        src_bf, Btcat, biascat, nullptr, proj, ROWS, 640, 256);

    // --- loc + softmax + deformable gather -> out_loc, attn_bf
    fused_gather_k<<<2048, blk, 0, stream>>>(proj, refp, out_loc, attn_bf);

    // --- output projection + residual(src) -> x1, LN1 (+bf16 copy)
    mfma_gemm_k<false, false, true><<<dim3(4, 64), blk, 0, stream>>>(
        attn_bf, pwT, pb, src, x1, ROWS, 256, 256);
    layernorm_k<true><<<2048, blk, 0, stream>>>(x1, g1, b1, x1_bf);

    // --- FFN ---
    mfma_gemm_k<true, true, false><<<dim3(16, 64), blk, 0, stream>>>(
        x1_bf, w1T, bi1, nullptr, hidden_bf, ROWS, 1024, 256);
    mfma_gemm_k<false, false, true><<<dim3(4, 64), blk, 0, stream>>>(
        hidden_bf, w2T, bi2, x1, out_x, ROWS, 256, 1024);
    layernorm_k<false><<<2048, blk, 0, stream>>>(out_x, g2, b2, nullptr);
}

// Round 4
// 243.294 us; speedup vs baseline: 1.9375x; 1.0082x over previous
//
#include <hip/hip_runtime.h>
#include <math.h>

#define ROWS   8192
#define LQ     4096
#define NHEAD  8
#define NLVL   4
#define NPTS   4
#define HDIM   32

typedef __attribute__((ext_vector_type(8))) short v8s;
typedef __attribute__((ext_vector_type(4))) float v4f;

__device__ __forceinline__ unsigned short f2bf(float x) {
    unsigned int u = __float_as_uint(x);
    u += 0x7fffu + ((u >> 16) & 1u);
    return (unsigned short)(u >> 16);
}
__device__ __forceinline__ float bf2f(unsigned short x) {
    return __uint_as_float(((unsigned int)x) << 16);
}

// ---------------------------------------------------------------------------
// fp32 -> bf16 elementwise (vectorized x4)
// ---------------------------------------------------------------------------
__global__ __launch_bounds__(256) void f2bf_k(const float* __restrict__ in,
                                              unsigned short* __restrict__ out, int n4)
{
    int i = blockIdx.x * 256 + threadIdx.x;
    if (i >= n4) return;
    float4 v = ((const float4*)in)[i];
    ushort4 o;
    o.x = f2bf(v.x); o.y = f2bf(v.y); o.z = f2bf(v.z); o.w = f2bf(v.w);
    ((ushort4*)out)[i] = o;
}

// ---------------------------------------------------------------------------
// Transpose + convert: out_bf[(n_off + n) * ldout + k] = bf16(in[k*N + n])
// ---------------------------------------------------------------------------
__global__ __launch_bounds__(256) void transT_k(const float* __restrict__ in,
                                                unsigned short* __restrict__ out,
                                                int K, int N, int ldout, int n_off)
{
    __shared__ float t[32][33];
    int tid = threadIdx.x;
    int tx = tid & 31, ty = tid >> 5;           // 32 x 8
    int k0 = blockIdx.y << 5, n0 = blockIdx.x << 5;
    #pragma unroll
    for (int i = 0; i < 4; i++)
        t[ty + i * 8][tx] = in[(size_t)(k0 + ty + i * 8) * N + n0 + tx];
    __syncthreads();
    #pragma unroll
    for (int i = 0; i < 4; i++)
        out[(size_t)(n_off + n0 + ty + i * 8) * ldout + k0 + tx] = f2bf(t[tx][ty + i * 8]);
}

// ---------------------------------------------------------------------------
// Concatenate 3 bias vectors (256 + 256 + 128)
// ---------------------------------------------------------------------------
__global__ __launch_bounds__(256) void biascat_k(const float* __restrict__ a,
                                                 const float* __restrict__ b,
                                                 const float* __restrict__ c,
                                                 float* __restrict__ out)
{
    int i = blockIdx.x * 256 + threadIdx.x;
    if (i < 256) out[i] = a[i];
    else if (i < 512) out[i] = b[i - 256];
    else if (i < 640) out[i] = c[i - 512];
}

// ---------------------------------------------------------------------------
// bf16 MFMA GEMM: C[M][N] = A[M][K] @ Bt[N][K]^T + bias (+res)(relu)
// BM=128, BN=64, BK=32; 256 threads = 4 waves (2x2), each wave 64x32 via
// 4x2 tiles of 16x16x32 MFMA. K-packed LDS: [kq][row][8].
// PROJ mode (N=640): cols [0,256) scatter as bf16 into compact value layout
// [ (b*4+l)*8+h ][pix][d] ; cols [256,640) -> po[row][col-256] fp32.
// ---------------------------------------------------------------------------
template<bool PROJ, bool OUTBF, bool RELU, bool RES>
__global__ __launch_bounds__(256) void mfma_gemm_k(
    const unsigned short* __restrict__ A,   // bf16 [M][K]
    const unsigned short* __restrict__ Bt,  // bf16 [N][K]
    const float* __restrict__ bias,
    const float* __restrict__ res,
    void* __restrict__ Cout,
    unsigned short* __restrict__ vbf,       // PROJ only
    int M, int N, int K)
{
    __shared__ __align__(16) unsigned short As[4][128][8];
    __shared__ __align__(16) unsigned short Bs[4][64][8];
    const int tid = threadIdx.x;
    const int row0 = blockIdx.y << 7, col0 = blockIdx.x << 6;
    const int wid = tid >> 6, lane = tid & 63;
    const int wm = wid & 1, wn = wid >> 1;
    const int lr = lane & 15, kq = lane >> 4;
    const int ar = tid >> 2, akq = tid & 3;
    const int bn = tid >> 2, bkq = tid & 3;

    v4f acc[4][2];
    #pragma unroll
    for (int i = 0; i < 4; i++)
        #pragma unroll
        for (int j = 0; j < 2; j++) acc[i][j] = (v4f){0.f, 0.f, 0.f, 0.f};

    for (int k0 = 0; k0 < K; k0 += 32) {
        float4 a0 = *(const float4*)(A + (size_t)(row0 + ar) * K + k0 + akq * 8);
        float4 a1 = *(const float4*)(A + (size_t)(row0 + ar + 64) * K + k0 + akq * 8);
        float4 b0 = *(const float4*)(Bt + (size_t)(col0 + bn) * K + k0 + bkq * 8);
        __syncthreads();
        *(float4*)(&As[akq][ar][0]) = a0;
        *(float4*)(&As[akq][ar + 64][0]) = a1;
        *(float4*)(&Bs[bkq][bn][0]) = b0;
        __syncthreads();
        v8s bf[2];
        #pragma unroll
        for (int nt = 0; nt < 2; nt++)
            bf[nt] = *(const v8s*)(&Bs[kq][wn * 32 + nt * 16 + lr][0]);
        #pragma unroll
        for (int mt = 0; mt < 4; mt++) {
            v8s af = *(const v8s*)(&As[kq][wm * 64 + mt * 16 + lr][0]);
            #pragma unroll
            for (int nt = 0; nt < 2; nt++)
                acc[mt][nt] = __builtin_amdgcn_mfma_f32_16x16x32_bf16(af, bf[nt], acc[mt][nt], 0, 0, 0);
        }
    }

    const int rq = lane >> 4;
    #pragma unroll
    for (int mt = 0; mt < 4; mt++) {
        #pragma unroll
        for (int nt = 0; nt < 2; nt++) {
            int col = col0 + wn * 32 + nt * 16 + lr;
            float bv = bias[col];
            #pragma unroll
            for (int i = 0; i < 4; i++) {
                int row = row0 + wm * 64 + mt * 16 + rq * 4 + i;
                float v = acc[mt][nt][i] + bv;
                if (RELU) v = fmaxf(v, 0.f);
                if (RES)  v += res[(size_t)row * N + col];
                if (PROJ) {
                    if (col0 < 256) {
                        // value head -> compact bf16 [ (b*4+l)*8+h ][pix][32]
                        int b = row >> 12, rb = row & 4095;
                        int l = rb >> 10, pix = rb & 1023;
                        int h = col >> 5, d = col & 31;
                        size_t idx = ((size_t)(((b << 2) + l) * 8 + h) << 15) + (pix << 5) + d;
                        vbf[idx] = f2bf(v);
                    } else {
                        ((float*)Cout)[(size_t)row * 384 + col - 256] = v;
                    }
                } else if (OUTBF) {
                    ((unsigned short*)Cout)[(size_t)row * N + col] = f2bf(v);
                } else {
                    ((float*)Cout)[(size_t)row * N + col] = v;
                }
            }
        }
    }
}

// ---------------------------------------------------------------------------
// Fused: sampling-loc compute (+write), softmax-16, bilinear gather.
// 8 lanes per (r,h) group; lane covers 4 dims (ushort4 = 8B; 8 lanes = 64B
// = exactly one cacheline per bilinear tap). value is compact bf16.
// ---------------------------------------------------------------------------
__global__ __launch_bounds__(256) void fused_gather_k(
    const float* __restrict__ po,              // [ROWS][384] offsets|logits
    const unsigned short* __restrict__ vbf,    // [64][1024][32] bf16
    const float* __restrict__ refp,            // [ROWS][8]
    float* __restrict__ out_loc,               // [ROWS][256]
    unsigned short* __restrict__ attn_bf)      // [ROWS][256] bf16
{
    int tid = threadIdx.x;
    int grp = tid >> 3, d4 = tid & 7;
    int gid = blockIdx.x * 32 + grp;           // r*8 + h
    int h = gid & 7, r = gid >> 3;
    int b = r >> 12;
    const float* prow = po + (size_t)r * 384;

    float rp[8];
    *(float4*)(rp)     = *(const float4*)(refp + (size_t)r * 8);
    *(float4*)(rp + 4) = *(const float4*)(refp + (size_t)r * 8 + 4);

    float loc[32];
    #pragma unroll
    for (int i = 0; i < 8; i++)
        *(float4*)(loc + i * 4) = *(const float4*)(prow + h * 32 + i * 4);
    #pragma unroll
    for (int i = 0; i < 32; i++) {
        int l = i >> 3, c = i & 1;
        loc[i] = rp[l * 2 + c] + loc[i] * (1.f / 32.f);
    }
    *(float4*)(out_loc + (size_t)r * 256 + h * 32 + d4 * 4) = *(const float4*)(loc + d4 * 4);

    float w[16];
    #pragma unroll
    for (int i = 0; i < 4; i++)
        *(float4*)(w + i * 4) = *(const float4*)(prow + 256 + h * 16 + i * 4);
    float m = -1e30f;
    #pragma unroll
    for (int i = 0; i < 16; i++) m = fmaxf(m, w[i]);
    float s = 0.f;
    #pragma unroll
    for (int i = 0; i < 16; i++) { w[i] = __expf(w[i] - m); s += w[i]; }
    float inv = 1.f / s;
    #pragma unroll
    for (int i = 0; i < 16; i++) w[i] *= inv;

    float4 acc = {0.f, 0.f, 0.f, 0.f};
    #pragma unroll
    for (int l = 0; l < 4; l++) {
        const unsigned short* vbase =
            vbf + (((size_t)(((b << 2) + l) * 8 + h)) << 15) + d4 * 4;
        #pragma unroll
        for (int p = 0; p < 4; p++) {
            float lx = loc[l * 8 + p * 2], ly = loc[l * 8 + p * 2 + 1];
            float wgt = w[l * 4 + p];
            float xf = lx * 32.f - 0.5f, yf = ly * 32.f - 0.5f;
            float x0f = floorf(xf), y0f = floorf(yf);
            float fx = xf - x0f, fy = yf - y0f;
            int x0 = (int)x0f, y0 = (int)y0f;
            #pragma unroll
            for (int dy = 0; dy < 2; dy++) {
                #pragma unroll
                for (int dx = 0; dx < 2; dx++) {
                    int xi = x0 + dx, yi = y0 + dy;
                    float wt = (dx ? fx : 1.f - fx) * (dy ? fy : 1.f - fy);
                    bool valid = (xi >= 0) & (xi < 32) & (yi >= 0) & (yi < 32);
                    int xc = min(max(xi, 0), 31), yc = min(max(yi, 0), 31);
                    float c = valid ? (wgt * wt) : 0.f;
                    ushort4 u = *(const ushort4*)(vbase + (size_t)((yc << 5) + xc) * 32);
                    acc.x += c * bf2f(u.x); acc.y += c * bf2f(u.y);
                    acc.z += c * bf2f(u.z); acc.w += c * bf2f(u.w);
                }
            }
        }
    }
    ushort4 o;
    o.x = f2bf(acc.x); o.y = f2bf(acc.y); o.z = f2bf(acc.z); o.w = f2bf(acc.w);
    *(ushort4*)(attn_bf + (size_t)r * 256 + h * 32 + d4 * 4) = o;
}

// ---------------------------------------------------------------------------
// In-place LayerNorm over 256 cols; optional bf16 copy-out.
// ---------------------------------------------------------------------------
template<bool WRITE_BF>
__global__ __launch_bounds__(256) void layernorm_k(
    float* __restrict__ x, const float* __restrict__ g, const float* __restrict__ b,
    unsigned short* __restrict__ xbf)
{
    int lane = threadIdx.x & 63;
    int wv = threadIdx.x >> 6;
    int row = blockIdx.x * 4 + wv;
    int c = lane << 2;
    float4 v = *(const float4*)(x + (size_t)row * 256 + c);
    float s = v.x + v.y + v.z + v.w;
    #pragma unroll
    for (int o = 1; o < 64; o <<= 1) s += __shfl_xor(s, o);
    float mu = s * (1.f / 256.f);
    float d0 = v.x - mu, d1 = v.y - mu, d2 = v.z - mu, d3 = v.w - mu;
    float vs = d0 * d0 + d1 * d1 + d2 * d2 + d3 * d3;
    #pragma unroll
    for (int o = 1; o < 64; o <<= 1) vs += __shfl_xor(vs, o);
    float rstd = rsqrtf(vs * (1.f / 256.f) + 1e-5f);
    float4 gg = *(const float4*)(g + c);
    float4 bb = *(const float4*)(b + c);
    float4 o4;
    o4.x = d0 * rstd * gg.x + bb.x;
    o4.y = d1 * rstd * gg.y + bb.y;
    o4.z = d2 * rstd * gg.z + bb.z;
    o4.w = d3 * rstd * gg.w + bb.w;
    *(float4*)(x + (size_t)row * 256 + c) = o4;
    if (WRITE_BF) {
        ushort4 ob;
        ob.x = f2bf(o4.x); ob.y = f2bf(o4.y); ob.z = f2bf(o4.z); ob.w = f2bf(o4.w);
        *(ushort4*)(xbf + (size_t)row * 256 + c) = ob;
    }
}

// ---------------------------------------------------------------------------
extern "C" void kernel_launch(void* const* d_in, const int* in_sizes, int n_in,
                              void* d_out, int out_size, void* d_ws, size_t ws_size,
                              hipStream_t stream)
{
    const float* src   = (const float*)d_in[0];
    const float* refp  = (const float*)d_in[2];
    const float* vw    = (const float*)d_in[3];
    const float* vb    = (const float*)d_in[4];
    const float* ofw   = (const float*)d_in[5];
    const float* ofb   = (const float*)d_in[6];
    const float* aww   = (const float*)d_in[7];
    const float* awb   = (const float*)d_in[8];
    const float* pw    = (const float*)d_in[9];
    const float* pb    = (const float*)d_in[10];
    const float* g1    = (const float*)d_in[11];
    const float* b1    = (const float*)d_in[12];
    const float* w1    = (const float*)d_in[13];
    const float* bi1   = (const float*)d_in[14];
    const float* w2    = (const float*)d_in[15];
    const float* bi2   = (const float*)d_in[16];
    const float* g2    = (const float*)d_in[17];
    const float* b2    = (const float*)d_in[18];

    float* ws = (float*)d_ws;
    float*          po        = ws;                               // 3,145,728 f
    float*          x1        = ws + 3145728;                     // 2,097,152 f
    unsigned short* value_bf  = (unsigned short*)(ws + 5242880);  // 2,097,152 us
    unsigned short* src_bf    = (unsigned short*)(ws + 6291456);  // 2,097,152 us
    unsigned short* x1_bf     = (unsigned short*)(ws + 7340032);
    unsigned short* attn_bf   = (unsigned short*)(ws + 8388608);
    unsigned short* hidden_bf = (unsigned short*)(ws + 9437184);  // 8,388,608 us
    unsigned short* Btcat     = (unsigned short*)(ws + 13631488); // 163,840 us
    unsigned short* pwT       = (unsigned short*)(ws + 13713408);
    unsigned short* w1T       = (unsigned short*)(ws + 13746176);
    unsigned short* w2T       = (unsigned short*)(ws + 13877248);
    float*          biascat   = ws + 14008320;                    // 640 f

    float* out_x   = (float*)d_out;
    float* out_loc = out_x + 2097152;

    dim3 blk(256);

    // --- weight prep (bf16, transposed) + src conversion ---
    f2bf_k<<<2048, blk, 0, stream>>>(src, src_bf, 524288);
    transT_k<<<dim3(8, 8),  blk, 0, stream>>>(vw,  Btcat, 256, 256,  256, 0);
    transT_k<<<dim3(8, 8),  blk, 0, stream>>>(ofw, Btcat, 256, 256,  256, 256);
    transT_k<<<dim3(4, 8),  blk, 0, stream>>>(aww, Btcat, 256, 128,  256, 512);
    transT_k<<<dim3(8, 8),  blk, 0, stream>>>(pw,  pwT,   256, 256,  256, 0);
    transT_k<<<dim3(32, 8), blk, 0, stream>>>(w1,  w1T,   256, 1024, 256, 0);
    transT_k<<<dim3(8, 32), blk, 0, stream>>>(w2,  w2T,  1024, 256, 1024, 0);
    biascat_k<<<3, blk, 0, stream>>>(vb, ofb, awb, biascat);

    // --- fused projections -> value_bf (compact) + po[8192][384]
    mfma_gemm_k<true, false, false, false><<<dim3(10, 64), blk, 0, stream>>>(
        src_bf, Btcat, biascat, nullptr, po, value_bf, ROWS, 640, 256);

    // --- loc + softmax + deformable gather -> out_loc, attn_bf
    fused_gather_k<<<2048, blk, 0, stream>>>(po, value_bf, refp, out_loc, attn_bf);

    // --- output projection + residual(src) -> x1, LN1 (+bf16 copy)
    mfma_gemm_k<false, false, false, true><<<dim3(4, 64), blk, 0, stream>>>(
        attn_bf, pwT, pb, src, x1, nullptr, ROWS, 256, 256);
    layernorm_k<true><<<2048, blk, 0, stream>>>(x1, g1, b1, x1_bf);

    // --- FFN ---
    mfma_gemm_k<false, true, true, false><<<dim3(16, 64), blk, 0, stream>>>(
        x1_bf, w1T, bi1, nullptr, hidden_bf, nullptr, ROWS, 1024, 256);
    mfma_gemm_k<false, false, false, true><<<dim3(4, 64), blk, 0, stream>>>(
        hidden_bf, w2T, bi2, x1, out_x, nullptr, ROWS, 256, 1024);
    layernorm_k<false><<<2048, blk, 0, stream>>>(out_x, g2, b2, nullptr);
}